// Round 7
// baseline (567.634 us; speedup 1.0000x reference)
//
#include <hip/hip_runtime.h>
#include <hip/hip_bf16.h>
#include <math.h>

// MambaRecurrence: B=4, L=2048, D_MODEL=2048, D_STATE=16, DT_RANK=128
// gemm1_fused: x_dbl = hs @ w1^T  — bf16 MFMA, in-register f32->bf16 conv of hs,
//              in-block K-split (1 wave per K/4) + LDS cross-wave reduce.
//              Output cols >=128 interleaved: [B0,C0,B1,C1,...] for float2 scan loads.
// gemm2_delta: delta = softplus(x_dbl[:,:128] @ w2^T + b), fp32 LDS-tiled,
//              epilogue transposes through LDS -> delta_t[b][d][t] (coalesced t).
// scan: depth-8 prefetch; delta = broadcast float4 loads; B/C float2; DPP reduce;
//       exp2 with A2 = A*log2e hoisted.

#define DM   2048
#define DS   16
#define RNK  128
#define XDW  160   // RNK + 2*DS
#define LSEQ 2048
#define NB   4
#define MTOT (NB * LSEQ)   // 8192

typedef __attribute__((ext_vector_type(8))) unsigned short u16x8;
typedef __attribute__((ext_vector_type(8))) short bf16x8;
typedef __attribute__((ext_vector_type(4))) float f32x4;

// ---------------- w1 -> bf16 (tiny, 160 blocks) ----------------
__global__ __launch_bounds__(256) void f32_to_bf16_kern(const float* __restrict__ in,
                                                        unsigned short* __restrict__ out) {
    const size_t i = ((size_t)blockIdx.x * 256 + threadIdx.x) * 8;
    const float4 v0 = *(const float4*)(in + i);
    const float4 v1 = *(const float4*)(in + i + 4);
    const float vv[8] = {v0.x, v0.y, v0.z, v0.w, v1.x, v1.y, v1.z, v1.w};
    u16x8 o;
    #pragma unroll
    for (int j = 0; j < 8; ++j) {
        __hip_bfloat16 h = __float2bfloat16(vv[j]);
        o[j] = *(unsigned short*)&h;
    }
    *(u16x8*)(out + i) = o;
}

__device__ __forceinline__ short bf16bits(float x) {
    __hip_bfloat16 h = __float2bfloat16(x);
    return *(short*)&h;
}

// ---------------- GEMM1 fused ----------------
// grid 512 (16 rows/block), block 256 = 4 waves; wave w covers K [512w, 512w+512).
// MFMA 16x16x32 bf16 layout (m89-verified): A lane row=l&15, k=(l>>4)*8+idx;
// B lane col=l&15 (w1 row = out col); D row=(l>>4)*4+r, col=l&15.
__global__ __launch_bounds__(256) void gemm1_fused(const float* __restrict__ hs,
                                                   const unsigned short* __restrict__ w1b,
                                                   float* __restrict__ xdbl) {
    __shared__ float red[4][16][162];
    const int w  = threadIdx.x >> 6;
    const int l  = threadIdx.x & 63;
    const int lr = l & 15;
    const int hk = (l >> 4) * 8;
    const int m0 = blockIdx.x * 16;

    f32x4 acc[10];
    #pragma unroll
    for (int j = 0; j < 10; ++j) acc[j] = (f32x4){0.f, 0.f, 0.f, 0.f};

    const float*          ap = hs  + (size_t)(m0 + lr) * DM + w * 512 + hk;
    const unsigned short* bp = w1b + (size_t)lr * DM        + w * 512 + hk;

    for (int ks = 0; ks < 16; ++ks) {
        const int kk = ks * 32;
        const float4 f0 = *(const float4*)(ap + kk);
        const float4 f1 = *(const float4*)(ap + kk + 4);
        const bf16x8 a = {bf16bits(f0.x), bf16bits(f0.y), bf16bits(f0.z), bf16bits(f0.w),
                          bf16bits(f1.x), bf16bits(f1.y), bf16bits(f1.z), bf16bits(f1.w)};
        #pragma unroll
        for (int j = 0; j < 10; ++j) {
            const bf16x8 b = *(const bf16x8*)(bp + (size_t)j * 16 * DM + kk);
            acc[j] = __builtin_amdgcn_mfma_f32_16x16x32_bf16(a, b, acc[j], 0, 0, 0);
        }
    }

    #pragma unroll
    for (int j = 0; j < 10; ++j)
        #pragma unroll
        for (int r = 0; r < 4; ++r)
            red[w][(l >> 4) * 4 + r][j * 16 + lr] = acc[j][r];
    __syncthreads();

    // cross-wave reduce + B/C interleave remap + store
    const int row = threadIdx.x >> 4;          // 0..15
    const int cb  = (threadIdx.x & 15) * 10;   // 0..150
    #pragma unroll
    for (int c = 0; c < 10; ++c) {
        const int col = cb + c;
        const float s = red[0][row][col] + red[1][row][col]
                      + red[2][row][col] + red[3][row][col];
        const int oc = (col < RNK)      ? col
                     : (col < RNK + DS) ? (RNK + 2 * (col - RNK))
                                        : (RNK + 2 * (col - RNK - DS) + 1);
        xdbl[(size_t)(m0 + row) * XDW + oc] = s;
    }
}

// ---------------- GEMM2 + softplus -> delta_t[b][d][t] ----------------
#define G2_BM 128
#define G2_BN 128
#define G2_BK 32
__global__ __launch_bounds__(256) void gemm2_delta(const float* __restrict__ xdbl,
                                                   const float* __restrict__ w2,
                                                   const float* __restrict__ bias,
                                                   float* __restrict__ delta_t) {
    __shared__ float xT[G2_BK][G2_BM + 4];
    __shared__ float wT[G2_BK][G2_BN + 4];
    __shared__ float sT[64][132];              // [d_local][t_local] transpose buffer
    const int m0 = blockIdx.x * G2_BM;         // t-rows (within one batch b)
    const int n0 = blockIdx.y * G2_BN;         // d-cols
    const int tid = threadIdx.x;
    const int tm = tid >> 4, tn = tid & 15;
    const int r0 = tm * 8;
    const int sk = (tid & 7) * 4;
    const int sr = tid >> 3;

    float acc[8][8];
    #pragma unroll
    for (int i = 0; i < 8; ++i)
        #pragma unroll
        for (int j = 0; j < 8; ++j) acc[i][j] = 0.f;

    for (int ch = 0; ch < RNK / G2_BK; ++ch) {
        const int kc = ch * G2_BK;
        __syncthreads();
        #pragma unroll
        for (int p = 0; p < 4; ++p) {
            const int row = sr + p * 32;
            const float4 v = *(const float4*)(xdbl + (size_t)(m0 + row) * XDW + kc + sk);
            xT[sk + 0][row] = v.x; xT[sk + 1][row] = v.y;
            xT[sk + 2][row] = v.z; xT[sk + 3][row] = v.w;
        }
        #pragma unroll
        for (int p = 0; p < 4; ++p) {
            const int row = sr + p * 32;
            const float4 v = *(const float4*)(w2 + (size_t)(n0 + row) * RNK + kc + sk);
            wT[sk + 0][row] = v.x; wT[sk + 1][row] = v.y;
            wT[sk + 2][row] = v.z; wT[sk + 3][row] = v.w;
        }
        __syncthreads();
        #pragma unroll 4
        for (int k = 0; k < G2_BK; ++k) {
            const float4 a0 = *(const float4*)&xT[k][r0];
            const float4 a1 = *(const float4*)&xT[k][r0 + 4];
            const float4 b0 = *(const float4*)&wT[k][tn * 4];
            const float4 b1 = *(const float4*)&wT[k][64 + tn * 4];
            const float av[8] = {a0.x,a0.y,a0.z,a0.w,a1.x,a1.y,a1.z,a1.w};
            const float bv[8] = {b0.x,b0.y,b0.z,b0.w,b1.x,b1.y,b1.z,b1.w};
            #pragma unroll
            for (int i = 0; i < 8; ++i)
                #pragma unroll
                for (int j = 0; j < 8; ++j)
                    acc[i][j] += av[i] * bv[j];
        }
    }

    // epilogue: softplus, transpose 128t x 64d halves through sT, coalesced t-stores
    const int b     = m0 / LSEQ;
    const int tloc0 = m0 % LSEQ;               // 2048 % 128 == 0 -> tile within one b
    #pragma unroll
    for (int hh = 0; hh < 2; ++hh) {
        if (hh) __syncthreads();               // half-0 reads done before refill
        #pragma unroll
        for (int i = 0; i < 8; ++i)
            #pragma unroll
            for (int jj = 0; jj < 4; ++jj) {
                const int j  = hh * 4 + jj;
                const int cl = tn * 4 + jj;    // 0..63 local d
                const float x = acc[i][j] + bias[n0 + hh * 64 + cl];
                sT[cl][r0 + i] = (x > 20.f) ? x : log1pf(expf(x));
            }
        __syncthreads();
        const int dl = tid >> 2;               // 0..63
        const int ts = (tid & 3) * 32;         // t segment
        float* dst = delta_t + ((size_t)b * DM + (n0 + hh * 64 + dl)) * LSEQ + tloc0 + ts;
        #pragma unroll
        for (int q = 0; q < 8; ++q)
            *(float4*)(dst + q * 4) = *(const float4*)&sT[dl][ts + q * 4];
    }
}

// ---------------- Selective scan ----------------
template<int CTRL>
__device__ __forceinline__ float dpp_addstep(float x) {
    const int yi = __builtin_amdgcn_update_dpp(0, __builtin_bit_cast(int, x),
                                               CTRL, 0xF, 0xF, true);
    return x + __builtin_bit_cast(float, yi);
}
__device__ __forceinline__ float red16(float x) {
    x = dpp_addstep<0xB1>(x);    // quad_perm xor1
    x = dpp_addstep<0x4E>(x);    // quad_perm xor2
    x = dpp_addstep<0x124>(x);   // row_ror:4
    x = dpp_addstep<0x128>(x);   // row_ror:8
    return x;
}

__global__ __launch_bounds__(256) void scan_kernel(const float* __restrict__ hs,
                                                   const float* __restrict__ xdbl,
                                                   const float* __restrict__ Alog,
                                                   const float* __restrict__ Dvec,
                                                   const float* __restrict__ delta_t,
                                                   float* __restrict__ y_out) {
    const int b = blockIdx.y;
    const int g = threadIdx.x >> 4;
    const int n = threadIdx.x & 15;
    const int d = blockIdx.x * 16 + g;

    const float A2 = -1.4426950408889634f * __expf(Alog[(size_t)d * DS + n]);
    const float Dd = Dvec[d];

    unsigned od = (unsigned)(b * LSEQ) * DM + (unsigned)d;               // u / y
    unsigned ob = (unsigned)(b * LSEQ) * XDW + (unsigned)(RNK + 2 * n);  // B,C float2

    const float* dp = delta_t + ((size_t)b * DM + d) * LSEQ;             // delta, t-contig
    float4 c0 = *(const float4*)(dp);
    float4 c1 = *(const float4*)(dp + 4);

    float  pu[8];
    float2 pbc[8];
    #pragma unroll
    for (int j = 0; j < 8; ++j) {
        pu[j]  = hs[od + j * DM];
        pbc[j] = *(const float2*)(xdbl + ob + j * XDW);
    }

    float h = 0.f;
    for (int t0 = 0; t0 < LSEQ - 8; t0 += 8) {
        const float4 nx0 = *(const float4*)(dp + 8);
        const float4 nx1 = *(const float4*)(dp + 12);
        const float dc[8] = {c0.x, c0.y, c0.z, c0.w, c1.x, c1.y, c1.z, c1.w};
        float pp[8], uD[8];
        #pragma unroll
        for (int j = 0; j < 8; ++j) {
            const float delta = dc[j];
            const float u     = pu[j];
            const float Bv    = pbc[j].x;
            const float Cv    = pbc[j].y;
            uD[j] = u * Dd;
            pu[j]  = hs[od + (8 + j) * DM];
            pbc[j] = *(const float2*)(xdbl + ob + (8 + j) * XDW);

            h = exp2f(delta * A2) * h + (delta * u) * Bv;
            pp[j] = h * Cv;
        }
        #pragma unroll
        for (int j = 0; j < 8; ++j) pp[j] = red16(pp[j]);
        float v = pp[0] + uD[0];
        #pragma unroll
        for (int j = 1; j < 8; ++j) v = (n == j) ? (pp[j] + uD[j]) : v;
        if (n < 8) y_out[od + (unsigned)n * DM] = v;
        od += 8 * DM;
        ob += 8 * XDW;
        dp += 8;
        c0 = nx0; c1 = nx1;
    }
    {   // peeled tail (t0 = LSEQ-8)
        const float dc[8] = {c0.x, c0.y, c0.z, c0.w, c1.x, c1.y, c1.z, c1.w};
        float pp[8], uD[8];
        #pragma unroll
        for (int j = 0; j < 8; ++j) {
            const float delta = dc[j];
            const float u     = pu[j];
            uD[j] = u * Dd;
            h = exp2f(delta * A2) * h + (delta * u) * pbc[j].x;
            pp[j] = h * pbc[j].y;
        }
        #pragma unroll
        for (int j = 0; j < 8; ++j) pp[j] = red16(pp[j]);
        float v = pp[0] + uD[0];
        #pragma unroll
        for (int j = 1; j < 8; ++j) v = (n == j) ? (pp[j] + uD[j]) : v;
        if (n < 8) y_out[od + (unsigned)n * DM] = v;
    }
}

extern "C" void kernel_launch(void* const* d_in, const int* in_sizes, int n_in,
                              void* d_out, int out_size, void* d_ws, size_t ws_size,
                              hipStream_t stream) {
    const float* hs   = (const float*)d_in[0];
    const float* w1   = (const float*)d_in[1];
    const float* w2   = (const float*)d_in[2];
    const float* bias = (const float*)d_in[3];
    const float* Alog = (const float*)d_in[4];
    const float* Dvec = (const float*)d_in[5];
    float* dout = (float*)d_out;

    // ws layout (73.0 MB total; R6 proved ws_size >= 82.6 MB):
    //   xdbl   fp32 [8192][160]          @ 0        (5,242,880 B)
    //   w1b    bf16 [160][2048]          @ 5242880  (655,360 B)
    //   delta_t fp32 [4][2048][2048]     @ 5898240  (67,108,864 B)
    float*          xdbl    = (float*)d_ws;
    unsigned short* w1b     = (unsigned short*)((char*)d_ws + 5242880);
    float*          delta_t = (float*)((char*)d_ws + 5898240);

    hipLaunchKernelGGL(f32_to_bf16_kern, dim3(XDW * DM / 8 / 256), dim3(256), 0, stream, w1, w1b);
    hipLaunchKernelGGL(gemm1_fused, dim3(MTOT / 16), dim3(256), 0, stream, hs, w1b, xdbl);
    hipLaunchKernelGGL(gemm2_delta, dim3(MTOT / G2_BM, DM / G2_BN), dim3(256), 0, stream,
                       xdbl, w2, bias, delta_t);
    hipLaunchKernelGGL(scan_kernel, dim3(DM / 16, NB), dim3(256), 0, stream,
                       hs, xdbl, Alog, Dvec, delta_t, dout);
}